// Round 8
// baseline (768.350 us; speedup 1.0000x reference)
//
#include <hip/hip_runtime.h>

#define TSTEPS 512   // LSTM sequence length (2048/4)
#define HID    64

__device__ __forceinline__ float sigm(float x) {
  return 1.0f / (1.0f + __expf(-x));
}
__device__ __forceinline__ float tanh_(float x) {
  return 1.0f - 2.0f / (1.0f + __expf(2.0f * x));
}

// ---------------------------------------------------------------------------
// Kernel 1: conv1 (3->16, k=3, same) + maxpool2.  x:[256,2048,3] -> t1:[256,1024,16]
// ---------------------------------------------------------------------------
__global__ __launch_bounds__(256) void conv1_pool(
    const float* __restrict__ x, const float* __restrict__ w,
    const float* __restrict__ bias, float* __restrict__ out) {
  __shared__ float ws[144];
  __shared__ float bs[16];
  const int tid = threadIdx.x;
  if (tid < 144) ws[tid] = w[tid];
  if (tid < 16)  bs[tid] = bias[tid];
  __syncthreads();

  const int idx = blockIdx.x * 256 + tid;   // b*1024 + t2
  const int b  = idx >> 10;
  const int t2 = idx & 1023;
  const float* xb = x + (size_t)b * 2048 * 3;
  const int p0 = 2 * t2;

  float xv[4][3];
#pragma unroll
  for (int j = 0; j < 4; ++j) {
    const int p = p0 - 1 + j;
    const bool ok = (p >= 0) && (p < 2048);
#pragma unroll
    for (int c = 0; c < 3; ++c) xv[j][c] = ok ? xb[p * 3 + c] : 0.0f;
  }

  float4 o4[4];
  float* op = (float*)o4;
#pragma unroll
  for (int o = 0; o < 16; ++o) {
    float s0 = bs[o], s1 = bs[o];
#pragma unroll
    for (int c = 0; c < 3; ++c) {
#pragma unroll
      for (int k = 0; k < 3; ++k) {
        const float wv = ws[(o * 3 + c) * 3 + k];
        s0 = fmaf(xv[k][c],     wv, s0);
        s1 = fmaf(xv[k + 1][c], wv, s1);
      }
    }
    op[o] = fmaxf(s0, s1);
  }
  float4* dst = (float4*)(out + (size_t)idx * 16);
  dst[0] = o4[0]; dst[1] = o4[1]; dst[2] = o4[2]; dst[3] = o4[3];
}

// ---------------------------------------------------------------------------
// Kernel 2: conv2 (16->32, k=3, same) + maxpool2. t1:[256,1024,16] -> feat:[256,512,32]
// ---------------------------------------------------------------------------
__global__ __launch_bounds__(256) void conv2_pool(
    const float* __restrict__ t1, const float* __restrict__ w,
    const float* __restrict__ bias, float* __restrict__ out) {
  __shared__ float ws[1536];
  __shared__ float bs[32];
  const int tid = threadIdx.x;
  for (int i = tid; i < 1536; i += 256) ws[i] = w[i];
  if (tid < 32) bs[tid] = bias[tid];
  __syncthreads();

  const int idx = blockIdx.x * 256 + tid;   // b*512 + t2
  const int b  = idx >> 9;
  const int t2 = idx & 511;
  const float* tb = t1 + (size_t)b * 1024 * 16;
  const int p0 = 2 * t2;

  float4 r4[4][4];
  float* r = (float*)r4;
#pragma unroll
  for (int j = 0; j < 4; ++j) {
    const int p = p0 - 1 + j;
    if (p >= 0 && p < 1024) {
      const float4* s = (const float4*)(tb + p * 16);
      r4[j][0] = s[0]; r4[j][1] = s[1]; r4[j][2] = s[2]; r4[j][3] = s[3];
    } else {
      const float4 z = {0.f, 0.f, 0.f, 0.f};
      r4[j][0] = z; r4[j][1] = z; r4[j][2] = z; r4[j][3] = z;
    }
  }

  float4 o4[8];
  float* op = (float*)o4;
#pragma unroll 4
  for (int o = 0; o < 32; ++o) {
    float s0 = bs[o], s1 = bs[o];
    const float* wo = &ws[o * 48];
#pragma unroll
    for (int c = 0; c < 16; ++c) {
      const float w0 = wo[c * 3], w1 = wo[c * 3 + 1], w2 = wo[c * 3 + 2];
      s0 = fmaf(r[0 * 16 + c], w0, s0);
      s0 = fmaf(r[1 * 16 + c], w1, s0);
      s0 = fmaf(r[2 * 16 + c], w2, s0);
      s1 = fmaf(r[1 * 16 + c], w0, s1);
      s1 = fmaf(r[2 * 16 + c], w1, s1);
      s1 = fmaf(r[3 * 16 + c], w2, s1);
    }
    op[o] = fmaxf(s0, s1);
  }
  float4* dst = (float4*)(out + (size_t)idx * 32);
#pragma unroll
  for (int q = 0; q < 8; ++q) dst[q] = o4[q];
}

// ---------------------------------------------------------------------------
// Kernel 2.5: pack LSTM weights into a unified row layout.
//   Wpack[r][0..127], biasv[r], r in [0,512):
//     r < 256 (layer0 row r):   [w_hh0_row(64) | w_ih0_row(32) | zeros(32)]
//     r >= 256 (layer1 row q):  [w_ih1_row(64) | w_hh1_row(64)]
// ---------------------------------------------------------------------------
__global__ __launch_bounds__(128) void pack_weights(
    const float* __restrict__ w_ih0, const float* __restrict__ w_hh0,
    const float* __restrict__ b_ih0, const float* __restrict__ b_hh0,
    const float* __restrict__ w_ih1, const float* __restrict__ w_hh1,
    const float* __restrict__ b_ih1, const float* __restrict__ b_hh1,
    float* __restrict__ Wpack, float* __restrict__ biasv) {
  const int r = blockIdx.x;    // 512 rows
  const int j = threadIdx.x;   // 128 cols
  float v;
  if (r < 256) {
    if (j < 64)      v = w_hh0[r * 64 + j];
    else if (j < 96) v = w_ih0[r * 32 + (j - 64)];
    else             v = 0.0f;
    if (j == 0) biasv[r] = b_ih0[r] + b_hh0[r];
  } else {
    const int q = r - 256;
    if (j < 64) v = w_ih1[q * 64 + j];
    else        v = w_hh1[q * 64 + (j - 64)];
    if (j == 0) biasv[r] = b_ih1[q] + b_hh1[q];
  }
  Wpack[r * 128 + j] = v;
}

// ---------------------------------------------------------------------------
// Kernel 3: fused 2-layer LSTM + fc.  One block per batch element, 16 waves
// (1024 threads, 4 waves/SIMD).  Each ROW's 128-MAC dot is SPLIT across two
// threads (half = tid>>9), so each thread holds only 16 float4 = 64 weight
// VGPRs -> total pressure ~100 < the 128-VGPR cap at 4 waves/EU -> the
// allocator has no reason to rematerialize the weight loads into the loop
// (the round-2..5 failure mode).  No inline-asm pinning (suspected cause of
// the round-6/7 toolchain failures).
//
//   half 0 (waves 0-7):   partial = W[r][0:64] . h0   (+bias) -> pre[0]
//   half 1, r<256 (8-11): partial = W[r][64:128] . x_t        -> pre[1]
//   half 1, r>=256(12-15):partial = W[r][64:128] . h1         -> pre[1]
// One barrier per step; update phase sums pre[0]+pre[1].  h0 kept privately
// by waves 0-7 (each runs the L0 update with its own c0); h1 by waves 12-15.
// ---------------------------------------------------------------------------
__global__ __launch_bounds__(1024, 4) void lstm_fused(
    const float* __restrict__ feat,
    const float* __restrict__ Wpack, const float* __restrict__ biasv,
    const float* __restrict__ fc_w, const float* __restrict__ fc_b,
    float* __restrict__ out) {
  __shared__ float4 featL[2056];      // 256 staged rows + 8 zero-pad float4
  __shared__ float  pre[2][2][512];   // [half][t&1][row], 8 KB
  __shared__ float  hbuf[16][128];    // per-wave private: [0..63]=h0, [64..127]=h1

  const int tid  = threadIdx.x;
  const int wv   = tid >> 6;          // wave id 0..15
  const int u    = tid & 63;          // lane
  const int b    = blockIdx.x;
  const int r    = tid & 511;         // packed gate-row
  const int half = tid >> 9;          // 0 = vA(h-side), 1 = vB side

  // ---- weight half-row -> 16 float4 in registers ----
  float4 wq[16];
  {
    const float4* wsrc = (const float4*)(Wpack + (size_t)r * 128 + half * 64);
#pragma unroll
    for (int k = 0; k < 16; ++k) wq[k] = wsrc[k];
  }
  const float bias = (half == 0) ? biasv[r] : 0.0f;

  // own-wave h-state init + featL zero-pad (visible after t=0 staging barrier)
  hbuf[wv][u]      = 0.0f;
  hbuf[wv][64 + u] = 0.0f;
  if (tid < 8) featL[2048 + tid] = (float4){0.f, 0.f, 0.f, 0.f};

  // gate-phase source (wave-uniform)
  const bool useFeat = (half == 1) && (r < 256);          // waves 8-11
  const float4* hsrc = (half == 0) ? (const float4*)&hbuf[wv][0]    // h0
                                   : (const float4*)&hbuf[wv][64];  // h1
  // update roles (wave-uniform)
  const bool doL0 = (wv < 8);          // keeps private h0/c0
  const bool doL1 = (wv >= 12);        // keeps private h1/c1

  const float4* fg = (const float4*)(feat + (size_t)b * TSTEPS * 32);
  float c0 = 0.0f, c1 = 0.0f;

  for (int t = 0; t <= TSTEPS; ++t) {
    // stage feat rows in 256-step halves (block-uniform branch)
    if ((t & 255) == 0 && t < TSTEPS) {
      if (t) __syncthreads();          // all waves done reading previous half
      const float4* src = fg + t * 8;
      featL[tid]        = src[tid];
      featL[tid + 1024] = src[tid + 1024];
      __syncthreads();                 // copy (and pad/h init) visible
    }

    // ---------- gate phase: 64-MAC half-dot (identical shape for all) ----------
    {
      const float4* vsrc = useFeat ? &featL[(t & 255) * 8] : hsrc;
      float a0 = bias, a1 = 0.f, a2 = 0.f, a3 = 0.f;
#pragma unroll
      for (int k = 0; k < 16; ++k) {
        const float4 v = vsrc[k];
        a0 = fmaf(wq[k].x, v.x, a0);
        a1 = fmaf(wq[k].y, v.y, a1);
        a2 = fmaf(wq[k].z, v.z, a2);
        a3 = fmaf(wq[k].w, v.w, a3);
      }
      pre[half][t & 1][r] = (a0 + a1) + (a2 + a3);
      // boundary-t values are garbage but never consumed
    }

    __syncthreads();   // the ONE barrier: both halves of pre[] visible

    // ---------- update phase ----------
    const int tb = t & 1;
    if (doL0 && t < TSTEPS) {          // layer0 update, private c0 per wave
      const float i = sigm (pre[0][tb][u]       + pre[1][tb][u]);
      const float f = sigm (pre[0][tb][64 + u]  + pre[1][tb][64 + u]);
      const float g = tanh_(pre[0][tb][128 + u] + pre[1][tb][128 + u]);
      const float o = sigm (pre[0][tb][192 + u] + pre[1][tb][192 + u]);
      c0 = fmaf(f, c0, i * g);
      hbuf[wv][u] = o * tanh_(c0);     // h0[t], own slot
    }
    if (doL1 && t >= 1) {              // layer1 update (time t-1), private c1
      const float i = sigm (pre[0][tb][256 + u] + pre[1][tb][256 + u]);
      const float f = sigm (pre[0][tb][320 + u] + pre[1][tb][320 + u]);
      const float g = tanh_(pre[0][tb][384 + u] + pre[1][tb][384 + u]);
      const float o = sigm (pre[0][tb][448 + u] + pre[1][tb][448 + u]);
      c1 = fmaf(f, c1, i * g);
      hbuf[wv][64 + u] = o * tanh_(c1);  // h1[t-1], own slot
    }
  }

  // fc epilogue: wave 12 wrote h1[T-1] into hbuf[12][64..127]; its lanes 0..4
  // read it (same-wave ordering, no barrier needed)
  if (wv == 12 && u < 5) {
    const float* h = &hbuf[12][64];
    float s = fc_b[u];
    const float* wr = fc_w + u * HID;
#pragma unroll
    for (int k = 0; k < HID; ++k) s = fmaf(wr[k], h[k], s);
    out[b * 5 + u] = s;
  }
}

// ---------------------------------------------------------------------------
extern "C" void kernel_launch(void* const* d_in, const int* in_sizes, int n_in,
                              void* d_out, int out_size, void* d_ws, size_t ws_size,
                              hipStream_t stream) {
  (void)in_sizes; (void)n_in; (void)out_size; (void)ws_size;
  const float* x    = (const float*)d_in[0];
  const float* c1w  = (const float*)d_in[1];
  const float* c1b  = (const float*)d_in[2];
  const float* c2w  = (const float*)d_in[3];
  const float* c2b  = (const float*)d_in[4];
  const float* wih0 = (const float*)d_in[5];
  const float* whh0 = (const float*)d_in[6];
  const float* bih0 = (const float*)d_in[7];
  const float* bhh0 = (const float*)d_in[8];
  const float* wih1 = (const float*)d_in[9];
  const float* whh1 = (const float*)d_in[10];
  const float* bih1 = (const float*)d_in[11];
  const float* bhh1 = (const float*)d_in[12];
  const float* fcw  = (const float*)d_in[13];
  const float* fcb  = (const float*)d_in[14];
  float* out = (float*)d_out;

  float* t1    = (float*)d_ws;                      // [256,1024,16] = 16 MB
  float* feat  = t1 + (size_t)256 * 1024 * 16;      // [256,512,32]  = 16 MB
  // Wpack/biasv reuse the t1 region (dead after conv2_pool; stream-ordered)
  float* Wpack = t1;                                // [512][128]
  float* biasv = t1 + 512 * 128;                    // [512]

  conv1_pool<<<1024, 256, 0, stream>>>(x, c1w, c1b, t1);
  conv2_pool<<<512, 256, 0, stream>>>(t1, c2w, c2b, feat);
  pack_weights<<<512, 128, 0, stream>>>(wih0, whh0, bih0, bhh0,
                                        wih1, whh1, bih1, bhh1, Wpack, biasv);
  lstm_fused<<<256, 1024, 0, stream>>>(feat, Wpack, biasv, fcw, fcb, out);
}